// Round 3
// baseline (4168.726 us; speedup 1.0000x reference)
//
#include <hip/hip_runtime.h>
#include <cstdint>
#include <cstddef>

namespace {

constexpr int B = 8, S = 256, V = 32000, H = 1024;
constexpr int BS = B * S;  // 2048
constexpr int NBLK = 128;  // rnn_scan grid; 128 blocks <= 256 CUs -> always all resident
constexpr int CPL = H / NBLK;  // cols per layer per block = 8

typedef __attribute__((ext_vector_type(8))) short bf16x8;
typedef __attribute__((ext_vector_type(4))) float f32x4;
typedef unsigned long long u64;

__device__ __forceinline__ unsigned short f2bf(float x) {
  union { float f; unsigned u; } v; v.f = x;
  unsigned r = v.u + 0x7fffu + ((v.u >> 16) & 1u);
  return (unsigned short)(r >> 16);
}

__device__ __forceinline__ u64 packtag(float v, unsigned tag) {
  return ((u64)tag << 32) | (u64)__float_as_uint(v);
}

// ---------------- prep kernels ----------------

__global__ __launch_bounds__(256) void k_zero(u64* __restrict__ p, long n) {
  long i = (long)blockIdx.x * 256 + threadIdx.x;
  const long stride = (long)gridDim.x * 256;
  for (; i < n; i += stride) p[i] = 0ull;
}

__global__ __launch_bounds__(256) void k_conv(const float* __restrict__ src,
                                              unsigned short* __restrict__ dst, int n) {
  int i = (blockIdx.x * 256 + threadIdx.x) * 4;
  if (i >= n) return;
  const float4 x = *(const float4*)(src + i);
  ushort4 o;
  o.x = f2bf(x.x); o.y = f2bf(x.y); o.z = f2bf(x.z); o.w = f2bf(x.w);
  *(ushort4*)(dst + i) = o;
}

__global__ __launch_bounds__(256) void k_transconv(const float* __restrict__ src,
                                                   unsigned short* __restrict__ dst) {
  __shared__ float t[32][33];
  int x0 = blockIdx.x * 32, y0 = blockIdx.y * 32;
  int tx = threadIdx.x & 31, ty = threadIdx.x >> 5;
  for (int i = ty; i < 32; i += 8)
    t[i][tx] = src[(size_t)(y0 + i) * H + x0 + tx];
  __syncthreads();
  for (int i = ty; i < 32; i += 8)
    dst[(size_t)(x0 + i) * H + y0 + tx] = f2bf(t[tx][i]);
}

__global__ __launch_bounds__(256) void k_gather(const int* __restrict__ tokens,
                                                const float* __restrict__ E,
                                                unsigned short* __restrict__ Xbf) {
  int m = blockIdx.x;
  int h = threadIdx.x * 4;
  int tok = tokens[m];
  const float4 x = *(const float4*)(E + (size_t)tok * H + h);
  ushort4 o; o.x = f2bf(x.x); o.y = f2bf(x.y); o.z = f2bf(x.z); o.w = f2bf(x.w);
  *(ushort4*)(Xbf + (size_t)m * H + h) = o;
}

__global__ __launch_bounds__(256) void k_prep(const float* __restrict__ Wi1,
                                              const float* __restrict__ bo0,
                                              const float* __restrict__ bi0,
                                              const float* __restrict__ bi1,
                                              const float* __restrict__ bh0,
                                              const float* __restrict__ bh1,
                                              float* __restrict__ c1,
                                              float* __restrict__ bsum0) {
  int i = blockIdx.x, t = threadIdx.x;
  int j = t * 4;
  float4 w = *(const float4*)(Wi1 + (size_t)i * H + j);
  float4 bv = *(const float4*)(bo0 + j);
  float a = w.x * bv.x + w.y * bv.y + w.z * bv.z + w.w * bv.w;
  #pragma unroll
  for (int o = 32; o; o >>= 1) a += __shfl_down(a, o, 64);
  __shared__ float red[4];
  if ((t & 63) == 0) red[t >> 6] = a;
  __syncthreads();
  if (t == 0) c1[i] = red[0] + red[1] + red[2] + red[3] + bi1[i] + bh1[i];
  if (t == 64) bsum0[i] = bi0[i] + bh0[i];
}

// ---------------- bf16 MFMA GEMM (unchanged) ----------------

__device__ __forceinline__ void async16(const unsigned short* g, unsigned short* l) {
  __builtin_amdgcn_global_load_lds(
      (const __attribute__((address_space(1))) unsigned int*)g,
      (__attribute__((address_space(3))) unsigned int*)l, 16, 0, 0);
}

template <int EPI>  // 0: +bias -> f32 ; 1: +bias -> bf16 ; 2: -> f32 (no bias)
__global__ __launch_bounds__(256) void gemm_bt(const unsigned short* __restrict__ A,
                                               const unsigned short* __restrict__ Bm,
                                               const float* __restrict__ bias,
                                               void* __restrict__ Cout,
                                               int Mrows, int N, int K) {
  __shared__ unsigned short sA[128 * 64];
  __shared__ unsigned short sB[128 * 64];
  const int bn = blockIdx.x, bm = blockIdx.y;
  const int tid = threadIdx.x;
  const int lane = tid & 63, wave = tid >> 6;
  const int wm = wave & 1, wn = wave >> 1;
  const int l15 = lane & 15, quad = lane >> 4;
  f32x4 acc[4][4] = {};

  const size_t row0 = (size_t)bm * 128, col0 = (size_t)bn * 128;

  int ldsbase[4], crow[4], ccol[4];
  #pragma unroll
  for (int i = 0; i < 4; ++i) {
    int g = i * 256 + wave * 64 + lane;
    int r = g >> 3;
    int c = (g & 7) ^ (r & 7);
    crow[i] = r; ccol[i] = c * 8;
    ldsbase[i] = (i * 256 + wave * 64) * 8;
  }

  const int kiters = K >> 6;
  for (int kt = 0; kt < kiters; ++kt) {
    __syncthreads();
    #pragma unroll
    for (int i = 0; i < 4; ++i) {
      const unsigned short* ga = A + (size_t)(row0 + crow[i]) * K + kt * 64 + ccol[i];
      async16(ga, &sA[ldsbase[i]]);
      const unsigned short* gb = Bm + (size_t)(col0 + crow[i]) * K + kt * 64 + ccol[i];
      async16(gb, &sB[ldsbase[i]]);
    }
    __syncthreads();
    #pragma unroll
    for (int kk = 0; kk < 2; ++kk) {
      bf16x8 af[4], bfr[4];
      #pragma unroll
      for (int sm = 0; sm < 4; ++sm) {
        int r = wm * 64 + sm * 16 + l15;
        int c = (kk * 4 + quad) ^ (r & 7);
        af[sm] = *(const bf16x8*)&sA[(r * 8 + c) * 8];
      }
      #pragma unroll
      for (int sn = 0; sn < 4; ++sn) {
        int r = wn * 64 + sn * 16 + l15;
        int c = (kk * 4 + quad) ^ (r & 7);
        bfr[sn] = *(const bf16x8*)&sB[(r * 8 + c) * 8];
      }
      #pragma unroll
      for (int sm = 0; sm < 4; ++sm)
        #pragma unroll
        for (int sn = 0; sn < 4; ++sn)
          acc[sm][sn] = __builtin_amdgcn_mfma_f32_16x16x32_bf16(af[sm], bfr[sn], acc[sm][sn], 0, 0, 0);
    }
  }

  #pragma unroll
  for (int sn = 0; sn < 4; ++sn) {
    const size_t col = col0 + wn * 64 + sn * 16 + l15;
    float bv = 0.f;
    if (EPI != 2) bv = bias[col];
    #pragma unroll
    for (int sm = 0; sm < 4; ++sm) {
      const size_t rb = row0 + wm * 64 + sm * 16 + quad * 4;
      #pragma unroll
      for (int r = 0; r < 4; ++r) {
        float v = acc[sm][sn][r] + bv;
        size_t off = (rb + r) * (size_t)N + col;
        if (EPI == 1) ((unsigned short*)Cout)[off] = f2bf(v);
        else          ((float*)Cout)[off] = v;
      }
    }
  }
}

// ---------------- self-timed dataflow recurrence, v5 ----------------
// v4 post-mortem: VALU time/tick identical across v3/v4 (~1.4us) -> the
// ~11us residual stall was the barrier PROTOCOL: 3-4 serialized MALL
// round trips per tick (h-store drain, flag store, poll, h-load).
// v5 removes the barrier entirely. Each h value is exchanged as ONE
// 8-byte atomic word {f32 value | u32 tick-tag}: tag==k implies the
// value is valid (single-word atomicity = free release/acquire).
// Consumers poll the data words directly -> ONE fabric round trip per
// tick. No flags, no gbar, no lockstep; slots are write-once so blocks
// may drift freely (monotone dataflow, deadlock-free: 128 blocks always
// resident on 256 CUs). TH arrays zeroed in-stream each launch: slot 0
// = {0.0, tag 0} = valid initial state; stale higher slots have tag 0 < k.
// Compute re-decomposed as (colpair x batch-half): 2 cols x 4 batches
// per thread -> halves per-thread LDS reads (32 ds_read_b128/tick).

__global__ __launch_bounds__(512) void rnn_scan(const float* __restrict__ A0,
                                                const float* __restrict__ Wh0,
                                                const float* __restrict__ Mm,
                                                const float* __restrict__ Wh1,
                                                const float* __restrict__ c1,
                                                u64* __restrict__ TH0,
                                                u64* __restrict__ TH1,
                                                unsigned short* __restrict__ HS1bf) {
  __shared__ float lh0[B * H];    // 32 KB  h0(k-1), [b][h]
  __shared__ float lh1[B * H];    // 32 KB  h1(k-2), [b][h]
  const int tid = threadIdx.x;
  const int blk = blockIdx.x;
  const int wave = tid >> 6, lane = tid & 63;
  const int cp = wave >> 1;             // colpair 0..3
  const int bh = wave & 1;              // batch half 0..1
  const int b0 = bh * 4;
  const int ca = blk * CPL + cp * 2;    // this wave's two columns: ca, ca+1
  const int cb = ca + 1;

  // ---- weights into registers, once: 2 cols x 16 j x {Wh0, Mm, Wh1} ----
  float4 w0a[4], w0b[4], wma[4], wmb[4], w1a[4], w1b[4];
  #pragma unroll
  for (int m = 0; m < 4; ++m) {
    const size_t oa = (size_t)ca * H + m * 256 + lane * 4;
    const size_t ob = (size_t)cb * H + m * 256 + lane * 4;
    w0a[m] = *(const float4*)(Wh0 + oa);  w0b[m] = *(const float4*)(Wh0 + ob);
    wma[m] = *(const float4*)(Mm + oa);   wmb[m] = *(const float4*)(Mm + ob);
    w1a[m] = *(const float4*)(Wh1 + oa);  w1b[m] = *(const float4*)(Wh1 + ob);
  }
  // finisher constants: layer0 -> lanes 0..7, layer1 -> lanes 8..15
  // lane&7 = idx: col = ca + (idx>>2), b = b0 + (idx&3)
  float c1v = 0.f;
  if (lane >= 8 && lane < 16) c1v = c1[ca + ((lane & 7) >> 2)];

  for (int k = 0; k <= S; ++k) {
    // layer0 epilogue operand (finisher lanes 0..7)
    float a0 = 0.f;
    if (k < S && lane < 8)
      a0 = A0[(size_t)((b0 + (lane & 3)) * S + k) * H + ca + (lane >> 2)];

    // ---- tagged poll-load of h0(k-1) and h1(k-2); value+tag in one 8B word ----
    const u64* g0 = TH0 + (size_t)k * (B * H);
    const u64* g1 = TH1 + (size_t)(k - 1) * (B * H);
    u64 wb0[16], wb1[16];
    #pragma unroll
    for (int i = 0; i < 16; ++i)
      wb0[i] = __hip_atomic_load(g0 + i * 512 + tid, __ATOMIC_RELAXED, __HIP_MEMORY_SCOPE_AGENT);
    if (k >= 1) {
      #pragma unroll
      for (int i = 0; i < 16; ++i)
        wb1[i] = __hip_atomic_load(g1 + i * 512 + tid, __ATOMIC_RELAXED, __HIP_MEMORY_SCOPE_AGENT);
    }
    #pragma unroll
    for (int i = 0; i < 16; ++i) {
      u64 w = wb0[i];
      while ((unsigned)(w >> 32) < (unsigned)k)
        w = __hip_atomic_load(g0 + i * 512 + tid, __ATOMIC_RELAXED, __HIP_MEMORY_SCOPE_AGENT);
      lh0[i * 512 + tid] = __uint_as_float((unsigned)w);
    }
    if (k >= 1) {
      #pragma unroll
      for (int i = 0; i < 16; ++i) {
        u64 w = wb1[i];
        while ((unsigned)(w >> 32) < (unsigned)(k - 1))
          w = __hip_atomic_load(g1 + i * 512 + tid, __ATOMIC_RELAXED, __HIP_MEMORY_SCOPE_AGENT);
        lh1[i * 512 + tid] = __uint_as_float((unsigned)w);
      }
    }
    __syncthreads();

    // ---- compute: register weights x LDS h; 2 cols x 4 batches per thread ----
    float p0[8], p1[8];   // [c*4 + b]
    #pragma unroll
    for (int b = 0; b < 4; ++b) {
      float4 h0m[4];
      #pragma unroll
      for (int m = 0; m < 4; ++m)
        h0m[m] = *(const float4*)&lh0[(b0 + b) * H + m * 256 + lane * 4];
      if (k < S) {
        float aa = 0.f, ab = 0.f;
        #pragma unroll
        for (int m = 0; m < 4; ++m) {
          aa += w0a[m].x * h0m[m].x + w0a[m].y * h0m[m].y +
                w0a[m].z * h0m[m].z + w0a[m].w * h0m[m].w;
          ab += w0b[m].x * h0m[m].x + w0b[m].y * h0m[m].y +
                w0b[m].z * h0m[m].z + w0b[m].w * h0m[m].w;
        }
        p0[b] = aa; p0[4 + b] = ab;
      }
      if (k >= 1) {
        float aa = 0.f, ab = 0.f;
        #pragma unroll
        for (int m = 0; m < 4; ++m) {
          float4 h1m = *(const float4*)&lh1[(b0 + b) * H + m * 256 + lane * 4];
          aa += wma[m].x * h0m[m].x + wma[m].y * h0m[m].y +
                wma[m].z * h0m[m].z + wma[m].w * h0m[m].w;
          aa += w1a[m].x * h1m.x + w1a[m].y * h1m.y +
                w1a[m].z * h1m.z + w1a[m].w * h1m.w;
          ab += wmb[m].x * h0m[m].x + wmb[m].y * h0m[m].y +
                wmb[m].z * h0m[m].z + wmb[m].w * h0m[m].w;
          ab += w1b[m].x * h1m.x + w1b[m].y * h1m.y +
                w1b[m].z * h1m.z + w1b[m].w * h1m.w;
        }
        p1[b] = aa; p1[4 + b] = ab;
      }
    }

    // ---- 64-lane butterfly reduction (all lanes get totals) ----
    if (k < S) {
      #pragma unroll
      for (int i = 0; i < 8; ++i) {
        float v = p0[i];
        v += __shfl_xor(v, 1, 64);  v += __shfl_xor(v, 2, 64);
        v += __shfl_xor(v, 4, 64);  v += __shfl_xor(v, 8, 64);
        v += __shfl_xor(v, 16, 64); v += __shfl_xor(v, 32, 64);
        p0[i] = v;
      }
    }
    if (k >= 1) {
      #pragma unroll
      for (int i = 0; i < 8; ++i) {
        float v = p1[i];
        v += __shfl_xor(v, 1, 64);  v += __shfl_xor(v, 2, 64);
        v += __shfl_xor(v, 4, 64);  v += __shfl_xor(v, 8, 64);
        v += __shfl_xor(v, 16, 64); v += __shfl_xor(v, 32, 64);
        p1[i] = v;
      }
    }

    // ---- finishers: tagged single-word stores (no barrier needed) ----
    if (k < S && lane < 8) {
      const int idx = lane & 7;
      float v = p0[0];
      #pragma unroll
      for (int i = 1; i < 8; ++i) if (idx == i) v = p0[i];
      v = tanhf(a0 + v);
      const int col = ca + (idx >> 2);
      const int b = b0 + (idx & 3);
      __hip_atomic_store(TH0 + (size_t)(k + 1) * (B * H) + b * H + col,
                         packtag(v, (unsigned)(k + 1)),
                         __ATOMIC_RELAXED, __HIP_MEMORY_SCOPE_AGENT);
    }
    if (k >= 1 && lane >= 8 && lane < 16) {
      const int idx = lane & 7;
      float v = p1[0];
      #pragma unroll
      for (int i = 1; i < 8; ++i) if (idx == i) v = p1[i];
      v = tanhf(c1v + v);
      const int col = ca + (idx >> 2);
      const int b = b0 + (idx & 3);
      __hip_atomic_store(TH1 + (size_t)k * (B * H) + b * H + col,
                         packtag(v, (unsigned)k),
                         __ATOMIC_RELAXED, __HIP_MEMORY_SCOPE_AGENT);
      HS1bf[(size_t)(b * S + (k - 1)) * H + col] = f2bf(v);  // plain store: read post-kernel
    }
    __syncthreads();  // protect lh0/lh1 against next tick's writes
  }
}

// ---------------- softmax ----------------

__global__ __launch_bounds__(256) void k_rowred(const float* __restrict__ Lg,
                                                float* __restrict__ rmax,
                                                float* __restrict__ rinv) {
  const int r = blockIdx.x;
  const float* p = Lg + (size_t)r * V;
  float m = -3.4e38f;
  for (int v = threadIdx.x * 4; v < V; v += 1024) {
    float4 x = *(const float4*)(p + v);
    m = fmaxf(m, fmaxf(fmaxf(x.x, x.y), fmaxf(x.z, x.w)));
  }
  #pragma unroll
  for (int o = 32; o; o >>= 1) m = fmaxf(m, __shfl_down(m, o, 64));
  __shared__ float sm_[4];
  __shared__ float bm;
  if ((threadIdx.x & 63) == 0) sm_[threadIdx.x >> 6] = m;
  __syncthreads();
  if (threadIdx.x == 0) bm = fmaxf(fmaxf(sm_[0], sm_[1]), fmaxf(sm_[2], sm_[3]));
  __syncthreads();
  m = bm;
  float s = 0.f;
  for (int v = threadIdx.x * 4; v < V; v += 1024) {
    float4 x = *(const float4*)(p + v);
    s += __expf(x.x - m) + __expf(x.y - m) + __expf(x.z - m) + __expf(x.w - m);
  }
  #pragma unroll
  for (int o = 32; o; o >>= 1) s += __shfl_down(s, o, 64);
  __syncthreads();
  if ((threadIdx.x & 63) == 0) sm_[threadIdx.x >> 6] = s;
  __syncthreads();
  if (threadIdx.x == 0) {
    rmax[r] = m;
    rinv[r] = 1.f / (sm_[0] + sm_[1] + sm_[2] + sm_[3]);
  }
}

__global__ __launch_bounds__(256) void k_norm(float* __restrict__ Lg,
                                              const float* __restrict__ rmax,
                                              const float* __restrict__ rinv) {
  const int r = blockIdx.y;
  const int v = blockIdx.x * 1024 + threadIdx.x * 4;
  if (v >= V) return;
  const float m = rmax[r], s = rinv[r];
  float* p = Lg + (size_t)r * V + v;
  float4 x = *(const float4*)p;
  x.x = __expf(x.x - m) * s;
  x.y = __expf(x.y - m) * s;
  x.z = __expf(x.z - m) * s;
  x.w = __expf(x.w - m) * s;
  *(float4*)p = x;
}

}  // namespace

extern "C" void kernel_launch(void* const* d_in, const int* in_sizes, int n_in,
                              void* d_out, int out_size, void* d_ws, size_t ws_size,
                              hipStream_t stream) {
  (void)in_sizes; (void)n_in; (void)out_size; (void)ws_size;
  const int*   tokens = (const int*)d_in[0];
  const float* E   = (const float*)d_in[1];
  const float* Wi  = (const float*)d_in[2];
  const float* bi  = (const float*)d_in[3];
  const float* Wh  = (const float*)d_in[4];
  const float* bh  = (const float*)d_in[5];
  const float* Wo  = (const float*)d_in[6];
  const float* bo  = (const float*)d_in[7];
  float* out = (float*)d_out;

  char* w = (char*)d_ws;
  auto alloc = [&](size_t bytes) { char* p = w; w += (bytes + 255) & ~(size_t)255; return p; };
  unsigned short* Ebf    = (unsigned short*)alloc((size_t)V * H * 2);
  unsigned short* Xbf    = (unsigned short*)alloc((size_t)BS * H * 2);
  unsigned short* Wi0bf  = (unsigned short*)alloc((size_t)H * H * 2);
  unsigned short* Wi1bf  = (unsigned short*)alloc((size_t)H * H * 2);
  unsigned short* Wo1bf  = (unsigned short*)alloc((size_t)H * H * 2);
  unsigned short* Wo0Tbf = (unsigned short*)alloc((size_t)H * H * 2);
  float* Mmat  = (float*)alloc((size_t)H * H * 4);
  float* A0f   = (float*)alloc((size_t)BS * H * 4);
  u64*   TH0   = (u64*)alloc((size_t)(S + 1) * B * H * 8);   // tagged {f32,tick}
  u64*   TH1   = (u64*)alloc((size_t)(S + 1) * B * H * 8);   // adjacent to TH0
  unsigned short* HS1bf = (unsigned short*)alloc((size_t)BS * H * 2);
  unsigned short* OUTbf = (unsigned short*)alloc((size_t)BS * H * 2);
  float* bsum0 = (float*)alloc(H * 4);
  float* c1v   = (float*)alloc(H * 4);
  float* rmax  = (float*)alloc(BS * 4);
  float* rinv  = (float*)alloc(BS * 4);

  const float* Wi0 = Wi;               const float* Wi1 = Wi + (size_t)H * H;
  const float* Wh0 = Wh;               const float* Wh1 = Wh + (size_t)H * H;
  const float* Wo0 = Wo;               const float* Wo1 = Wo + (size_t)H * H;
  const float* bi0 = bi;  const float* bi1 = bi + H;
  const float* bh0 = bh;  const float* bh1 = bh + H;
  const float* bo0 = bo;  const float* bo1 = bo + H;

  const long thn = 2L * (S + 1) * B * H;  // TH0+TH1 are adjacent
  k_zero<<<dim3(2048), dim3(256), 0, stream>>>(TH0, thn);
  k_conv<<<dim3((V * H) / 1024), dim3(256), 0, stream>>>(E, Ebf, V * H);
  k_conv<<<dim3((H * H) / 1024), dim3(256), 0, stream>>>(Wi0, Wi0bf, H * H);
  k_conv<<<dim3((H * H) / 1024), dim3(256), 0, stream>>>(Wi1, Wi1bf, H * H);
  k_conv<<<dim3((H * H) / 1024), dim3(256), 0, stream>>>(Wo1, Wo1bf, H * H);
  k_transconv<<<dim3(32, 32), dim3(256), 0, stream>>>(Wo0, Wo0Tbf);
  k_gather<<<dim3(BS), dim3(256), 0, stream>>>(tokens, E, Xbf);
  k_prep<<<dim3(H), dim3(256), 0, stream>>>(Wi1, bo0, bi0, bi1, bh0, bh1,
                                            c1v, bsum0);

  gemm_bt<2><<<dim3(8, 8), dim3(256), 0, stream>>>(Wi1bf, Wo0Tbf, nullptr, Mmat, H, H, H);
  gemm_bt<0><<<dim3(8, 16), dim3(256), 0, stream>>>(Xbf, Wi0bf, bsum0, A0f, BS, H, H);

  rnn_scan<<<dim3(NBLK), dim3(512), 0, stream>>>(A0f, Wh0, Mmat, Wh1, c1v,
                                                 TH0, TH1, HS1bf);

  gemm_bt<1><<<dim3(8, 16), dim3(256), 0, stream>>>(HS1bf, Wo1bf, bo1, OUTbf, BS, H, H);
  gemm_bt<2><<<dim3(250, 16), dim3(256), 0, stream>>>(OUTbf, Ebf, nullptr, out, BS, V, H);

  k_rowred<<<dim3(BS), dim3(256), 0, stream>>>(out, rmax, rinv);
  k_norm<<<dim3(32, BS), dim3(256), 0, stream>>>(out, rmax, rinv);
}

// Round 4
// 2032.474 us; speedup vs baseline: 2.0511x; 2.0511x over previous
//
#include <hip/hip_runtime.h>
#include <cstdint>
#include <cstddef>

namespace {

constexpr int B = 8, S = 256, V = 32000, H = 1024;
constexpr int BS = B * S;  // 2048
constexpr int NBLK = 256;        // rnn_scan grid: 8 groups x 32 blocks, 1/CU
constexpr int BPB = 32;          // blocks per batch-group
constexpr int CPB = H / BPB;     // cols per block per layer = 32
constexpr int CPW = 4;           // cols per wave (8 waves x 4 = 32)

typedef __attribute__((ext_vector_type(8))) short bf16x8;
typedef __attribute__((ext_vector_type(4))) float f32x4;
typedef unsigned long long u64;

__device__ __forceinline__ unsigned short f2bf(float x) {
  union { float f; unsigned u; } v; v.f = x;
  unsigned r = v.u + 0x7fffu + ((v.u >> 16) & 1u);
  return (unsigned short)(r >> 16);
}

__device__ __forceinline__ u64 packtag(float v, unsigned tag) {
  return ((u64)tag << 32) | (u64)__float_as_uint(v);
}

// ---------------- prep kernels ----------------

__global__ __launch_bounds__(256) void k_zero(u64* __restrict__ p, long n) {
  long i = (long)blockIdx.x * 256 + threadIdx.x;
  const long stride = (long)gridDim.x * 256;
  for (; i < n; i += stride) p[i] = 0ull;
}

__global__ __launch_bounds__(256) void k_conv(const float* __restrict__ src,
                                              unsigned short* __restrict__ dst, int n) {
  int i = (blockIdx.x * 256 + threadIdx.x) * 4;
  if (i >= n) return;
  const float4 x = *(const float4*)(src + i);
  ushort4 o;
  o.x = f2bf(x.x); o.y = f2bf(x.y); o.z = f2bf(x.z); o.w = f2bf(x.w);
  *(ushort4*)(dst + i) = o;
}

__global__ __launch_bounds__(256) void k_transconv(const float* __restrict__ src,
                                                   unsigned short* __restrict__ dst) {
  __shared__ float t[32][33];
  int x0 = blockIdx.x * 32, y0 = blockIdx.y * 32;
  int tx = threadIdx.x & 31, ty = threadIdx.x >> 5;
  for (int i = ty; i < 32; i += 8)
    t[i][tx] = src[(size_t)(y0 + i) * H + x0 + tx];
  __syncthreads();
  for (int i = ty; i < 32; i += 8)
    dst[(size_t)(x0 + i) * H + y0 + tx] = f2bf(t[tx][i]);
}

__global__ __launch_bounds__(256) void k_gather(const int* __restrict__ tokens,
                                                const float* __restrict__ E,
                                                unsigned short* __restrict__ Xbf) {
  int m = blockIdx.x;
  int h = threadIdx.x * 4;
  int tok = tokens[m];
  const float4 x = *(const float4*)(E + (size_t)tok * H + h);
  ushort4 o; o.x = f2bf(x.x); o.y = f2bf(x.y); o.z = f2bf(x.z); o.w = f2bf(x.w);
  *(ushort4*)(Xbf + (size_t)m * H + h) = o;
}

__global__ __launch_bounds__(256) void k_prep(const float* __restrict__ Wi1,
                                              const float* __restrict__ bo0,
                                              const float* __restrict__ bi0,
                                              const float* __restrict__ bi1,
                                              const float* __restrict__ bh0,
                                              const float* __restrict__ bh1,
                                              float* __restrict__ c1,
                                              float* __restrict__ bsum0) {
  int i = blockIdx.x, t = threadIdx.x;
  int j = t * 4;
  float4 w = *(const float4*)(Wi1 + (size_t)i * H + j);
  float4 bv = *(const float4*)(bo0 + j);
  float a = w.x * bv.x + w.y * bv.y + w.z * bv.z + w.w * bv.w;
  #pragma unroll
  for (int o = 32; o; o >>= 1) a += __shfl_down(a, o, 64);
  __shared__ float red[4];
  if ((t & 63) == 0) red[t >> 6] = a;
  __syncthreads();
  if (t == 0) c1[i] = red[0] + red[1] + red[2] + red[3] + bi1[i] + bh1[i];
  if (t == 64) bsum0[i] = bi0[i] + bh0[i];
}

// ---------------- bf16 MFMA GEMM (unchanged) ----------------

__device__ __forceinline__ void async16(const unsigned short* g, unsigned short* l) {
  __builtin_amdgcn_global_load_lds(
      (const __attribute__((address_space(1))) unsigned int*)g,
      (__attribute__((address_space(3))) unsigned int*)l, 16, 0, 0);
}

template <int EPI>  // 0: +bias -> f32 ; 1: +bias -> bf16 ; 2: -> f32 (no bias)
__global__ __launch_bounds__(256) void gemm_bt(const unsigned short* __restrict__ A,
                                               const unsigned short* __restrict__ Bm,
                                               const float* __restrict__ bias,
                                               void* __restrict__ Cout,
                                               int Mrows, int N, int K) {
  __shared__ unsigned short sA[128 * 64];
  __shared__ unsigned short sB[128 * 64];
  const int bn = blockIdx.x, bm = blockIdx.y;
  const int tid = threadIdx.x;
  const int lane = tid & 63, wave = tid >> 6;
  const int wm = wave & 1, wn = wave >> 1;
  const int l15 = lane & 15, quad = lane >> 4;
  f32x4 acc[4][4] = {};

  const size_t row0 = (size_t)bm * 128, col0 = (size_t)bn * 128;

  int ldsbase[4], crow[4], ccol[4];
  #pragma unroll
  for (int i = 0; i < 4; ++i) {
    int g = i * 256 + wave * 64 + lane;
    int r = g >> 3;
    int c = (g & 7) ^ (r & 7);
    crow[i] = r; ccol[i] = c * 8;
    ldsbase[i] = (i * 256 + wave * 64) * 8;
  }

  const int kiters = K >> 6;
  for (int kt = 0; kt < kiters; ++kt) {
    __syncthreads();
    #pragma unroll
    for (int i = 0; i < 4; ++i) {
      const unsigned short* ga = A + (size_t)(row0 + crow[i]) * K + kt * 64 + ccol[i];
      async16(ga, &sA[ldsbase[i]]);
      const unsigned short* gb = Bm + (size_t)(col0 + crow[i]) * K + kt * 64 + ccol[i];
      async16(gb, &sB[ldsbase[i]]);
    }
    __syncthreads();
    #pragma unroll
    for (int kk = 0; kk < 2; ++kk) {
      bf16x8 af[4], bfr[4];
      #pragma unroll
      for (int sm = 0; sm < 4; ++sm) {
        int r = wm * 64 + sm * 16 + l15;
        int c = (kk * 4 + quad) ^ (r & 7);
        af[sm] = *(const bf16x8*)&sA[(r * 8 + c) * 8];
      }
      #pragma unroll
      for (int sn = 0; sn < 4; ++sn) {
        int r = wn * 64 + sn * 16 + l15;
        int c = (kk * 4 + quad) ^ (r & 7);
        bfr[sn] = *(const bf16x8*)&sB[(r * 8 + c) * 8];
      }
      #pragma unroll
      for (int sm = 0; sm < 4; ++sm)
        #pragma unroll
        for (int sn = 0; sn < 4; ++sn)
          acc[sm][sn] = __builtin_amdgcn_mfma_f32_16x16x32_bf16(af[sm], bfr[sn], acc[sm][sn], 0, 0, 0);
    }
  }

  #pragma unroll
  for (int sn = 0; sn < 4; ++sn) {
    const size_t col = col0 + wn * 64 + sn * 16 + l15;
    float bv = 0.f;
    if (EPI != 2) bv = bias[col];
    #pragma unroll
    for (int sm = 0; sm < 4; ++sm) {
      const size_t rb = row0 + wm * 64 + sm * 16 + quad * 4;
      #pragma unroll
      for (int r = 0; r < 4; ++r) {
        float v = acc[sm][sn][r] + bv;
        size_t off = (rb + r) * (size_t)N + col;
        if (EPI == 1) ((unsigned short*)Cout)[off] = f2bf(v);
        else          ((float*)Cout)[off] = v;
      }
    }
  }
}

// ---------------- batch-partitioned dataflow recurrence, v6 ----------------
// v5 post-mortem: all three sync protocols land at ~12-17us/tick -> the cost
// is the DEPENDENCY STRUCTURE (all-to-all: every block needs all 8192 h
// values each tick; 16.8 MB/tick fabric traffic; 32 dependent poll loads
// per thread), not the protocol. But h @ W^T is row-wise: batch chains are
// COMPLETELY INDEPENDENT. v6: 256 blocks = 8 groups x 32; group g runs
// batch g alone. Each block owns 32 cols of both layers; weights stay in
// 192 VGPRs (4 cols/wave x 16 j/lane x 3 mats). Per tick per block the
// exchange is 16 KB (vs 128 KB), 4 dependent polls per thread (vs 32),
// 4 MB/tick total fabric traffic (vs 16.8), and the 8 groups drift
// independently. Tagged {f32|tick} single-word scheme carried from v5
// (validated): tag==k implies valid, zero-init = valid initial state.

__global__ __launch_bounds__(512) void rnn_scan(const float* __restrict__ A0,
                                                const float* __restrict__ Wh0,
                                                const float* __restrict__ Mm,
                                                const float* __restrict__ Wh1,
                                                const float* __restrict__ c1,
                                                u64* __restrict__ TH0,
                                                u64* __restrict__ TH1,
                                                unsigned short* __restrict__ HS1bf) {
  __shared__ float lh0[H];   // 4 KB  h0(k-1) for this batch
  __shared__ float lh1[H];   // 4 KB  h1(k-2) for this batch
  const int tid = threadIdx.x;
  const int bb = blockIdx.x >> 5;        // batch 0..7
  const int blk32 = blockIdx.x & 31;     // block within group
  const int wave = tid >> 6, lane = tid & 63;
  const int colb = blk32 * CPB + wave * CPW;   // this wave's 4 cols
  const size_t bOff = (size_t)bb * (S + 1);

  // ---- weights into registers, once: 4 cols x 16 j x {Wh0, Mm, Wh1} ----
  float4 w0[4][4], wm[4][4], w1[4][4];
  #pragma unroll
  for (int c = 0; c < 4; ++c) {
    #pragma unroll
    for (int m = 0; m < 4; ++m) {
      const size_t o = (size_t)(colb + c) * H + m * 256 + lane * 4;
      w0[c][m] = *(const float4*)(Wh0 + o);
      wm[c][m] = *(const float4*)(Mm + o);
      w1[c][m] = *(const float4*)(Wh1 + o);
    }
  }
  // finishers: lanes 0..3 -> layer0 col colb+lane; lanes 4..7 -> layer1 col colb+lane-4
  float c1v = 0.f;
  if (lane >= 4 && lane < 8) c1v = c1[colb + lane - 4];

  for (int k = 0; k <= S; ++k) {
    // layer0 epilogue operand
    float a0 = 0.f;
    if (k < S && lane < 4)
      a0 = A0[((size_t)bb * S + k) * H + colb + lane];

    // ---- tagged poll-load: 2 words of h0(k), 2 words of h1(k-1) per thread ----
    const u64* g0 = TH0 + (bOff + k) * H + 2 * tid;
    u64 x0 = __hip_atomic_load(g0, __ATOMIC_RELAXED, __HIP_MEMORY_SCOPE_AGENT);
    u64 x1 = __hip_atomic_load(g0 + 1, __ATOMIC_RELAXED, __HIP_MEMORY_SCOPE_AGENT);
    u64 y0 = 0, y1 = 0;
    const u64* g1 = TH1 + (bOff + (k - 1)) * H + 2 * tid;
    if (k >= 1) {
      y0 = __hip_atomic_load(g1, __ATOMIC_RELAXED, __HIP_MEMORY_SCOPE_AGENT);
      y1 = __hip_atomic_load(g1 + 1, __ATOMIC_RELAXED, __HIP_MEMORY_SCOPE_AGENT);
    }
    while ((unsigned)(x0 >> 32) < (unsigned)k)
      x0 = __hip_atomic_load(g0, __ATOMIC_RELAXED, __HIP_MEMORY_SCOPE_AGENT);
    while ((unsigned)(x1 >> 32) < (unsigned)k)
      x1 = __hip_atomic_load(g0 + 1, __ATOMIC_RELAXED, __HIP_MEMORY_SCOPE_AGENT);
    lh0[2 * tid] = __uint_as_float((unsigned)x0);
    lh0[2 * tid + 1] = __uint_as_float((unsigned)x1);
    if (k >= 1) {
      while ((unsigned)(y0 >> 32) < (unsigned)(k - 1))
        y0 = __hip_atomic_load(g1, __ATOMIC_RELAXED, __HIP_MEMORY_SCOPE_AGENT);
      while ((unsigned)(y1 >> 32) < (unsigned)(k - 1))
        y1 = __hip_atomic_load(g1 + 1, __ATOMIC_RELAXED, __HIP_MEMORY_SCOPE_AGENT);
      lh1[2 * tid] = __uint_as_float((unsigned)y0);
      lh1[2 * tid + 1] = __uint_as_float((unsigned)y1);
    }
    __syncthreads();

    // ---- compute: register weights x LDS h; 4 cols, both layers ----
    float4 h0m[4];
    #pragma unroll
    for (int m = 0; m < 4; ++m)
      h0m[m] = *(const float4*)&lh0[m * 256 + lane * 4];

    float p0[4] = {0.f, 0.f, 0.f, 0.f}, p1[4] = {0.f, 0.f, 0.f, 0.f};
    if (k < S) {
      #pragma unroll
      for (int c = 0; c < 4; ++c)
        #pragma unroll
        for (int m = 0; m < 4; ++m)
          p0[c] += w0[c][m].x * h0m[m].x + w0[c][m].y * h0m[m].y +
                   w0[c][m].z * h0m[m].z + w0[c][m].w * h0m[m].w;
    }
    if (k >= 1) {
      #pragma unroll
      for (int c = 0; c < 4; ++c)
        #pragma unroll
        for (int m = 0; m < 4; ++m)
          p1[c] += wm[c][m].x * h0m[m].x + wm[c][m].y * h0m[m].y +
                   wm[c][m].z * h0m[m].z + wm[c][m].w * h0m[m].w;
      #pragma unroll
      for (int m = 0; m < 4; ++m) {
        const float4 h1m = *(const float4*)&lh1[m * 256 + lane * 4];
        #pragma unroll
        for (int c = 0; c < 4; ++c)
          p1[c] += w1[c][m].x * h1m.x + w1[c][m].y * h1m.y +
                   w1[c][m].z * h1m.z + w1[c][m].w * h1m.w;
      }
    }

    // ---- 64-lane butterfly reduction ----
    if (k < S) {
      #pragma unroll
      for (int i = 0; i < 4; ++i) {
        float v = p0[i];
        v += __shfl_xor(v, 1, 64);  v += __shfl_xor(v, 2, 64);
        v += __shfl_xor(v, 4, 64);  v += __shfl_xor(v, 8, 64);
        v += __shfl_xor(v, 16, 64); v += __shfl_xor(v, 32, 64);
        p0[i] = v;
      }
    }
    if (k >= 1) {
      #pragma unroll
      for (int i = 0; i < 4; ++i) {
        float v = p1[i];
        v += __shfl_xor(v, 1, 64);  v += __shfl_xor(v, 2, 64);
        v += __shfl_xor(v, 4, 64);  v += __shfl_xor(v, 8, 64);
        v += __shfl_xor(v, 16, 64); v += __shfl_xor(v, 32, 64);
        p1[i] = v;
      }
    }

    // ---- finishers: tagged single-word stores ----
    if (k < S && lane < 4) {
      float v = p0[0];
      #pragma unroll
      for (int i = 1; i < 4; ++i) if (lane == i) v = p0[i];
      v = tanhf(a0 + v);
      __hip_atomic_store(TH0 + (bOff + k + 1) * H + colb + lane,
                         packtag(v, (unsigned)(k + 1)),
                         __ATOMIC_RELAXED, __HIP_MEMORY_SCOPE_AGENT);
    }
    if (k >= 1 && lane >= 4 && lane < 8) {
      const int c = lane - 4;
      float v = p1[0];
      #pragma unroll
      for (int i = 1; i < 4; ++i) if (c == i) v = p1[i];
      v = tanhf(c1v + v);
      __hip_atomic_store(TH1 + (bOff + k) * H + colb + c,
                         packtag(v, (unsigned)k),
                         __ATOMIC_RELAXED, __HIP_MEMORY_SCOPE_AGENT);
      HS1bf[((size_t)bb * S + (k - 1)) * H + colb + c] = f2bf(v);  // plain: read post-kernel
    }
    __syncthreads();  // protect lh0/lh1 against next tick's writes
  }
}

// ---------------- softmax ----------------

__global__ __launch_bounds__(256) void k_rowred(const float* __restrict__ Lg,
                                                float* __restrict__ rmax,
                                                float* __restrict__ rinv) {
  const int r = blockIdx.x;
  const float* p = Lg + (size_t)r * V;
  float m = -3.4e38f;
  for (int v = threadIdx.x * 4; v < V; v += 1024) {
    float4 x = *(const float4*)(p + v);
    m = fmaxf(m, fmaxf(fmaxf(x.x, x.y), fmaxf(x.z, x.w)));
  }
  #pragma unroll
  for (int o = 32; o; o >>= 1) m = fmaxf(m, __shfl_down(m, o, 64));
  __shared__ float sm_[4];
  __shared__ float bm;
  if ((threadIdx.x & 63) == 0) sm_[threadIdx.x >> 6] = m;
  __syncthreads();
  if (threadIdx.x == 0) bm = fmaxf(fmaxf(sm_[0], sm_[1]), fmaxf(sm_[2], sm_[3]));
  __syncthreads();
  m = bm;
  float s = 0.f;
  for (int v = threadIdx.x * 4; v < V; v += 1024) {
    float4 x = *(const float4*)(p + v);
    s += __expf(x.x - m) + __expf(x.y - m) + __expf(x.z - m) + __expf(x.w - m);
  }
  #pragma unroll
  for (int o = 32; o; o >>= 1) s += __shfl_down(s, o, 64);
  __syncthreads();
  if ((threadIdx.x & 63) == 0) sm_[threadIdx.x >> 6] = s;
  __syncthreads();
  if (threadIdx.x == 0) {
    rmax[r] = m;
    rinv[r] = 1.f / (sm_[0] + sm_[1] + sm_[2] + sm_[3]);
  }
}

__global__ __launch_bounds__(256) void k_norm(float* __restrict__ Lg,
                                              const float* __restrict__ rmax,
                                              const float* __restrict__ rinv) {
  const int r = blockIdx.y;
  const int v = blockIdx.x * 1024 + threadIdx.x * 4;
  if (v >= V) return;
  const float m = rmax[r], s = rinv[r];
  float* p = Lg + (size_t)r * V + v;
  float4 x = *(const float4*)p;
  x.x = __expf(x.x - m) * s;
  x.y = __expf(x.y - m) * s;
  x.z = __expf(x.z - m) * s;
  x.w = __expf(x.w - m) * s;
  *(float4*)p = x;
}

}  // namespace

extern "C" void kernel_launch(void* const* d_in, const int* in_sizes, int n_in,
                              void* d_out, int out_size, void* d_ws, size_t ws_size,
                              hipStream_t stream) {
  (void)in_sizes; (void)n_in; (void)out_size; (void)ws_size;
  const int*   tokens = (const int*)d_in[0];
  const float* E   = (const float*)d_in[1];
  const float* Wi  = (const float*)d_in[2];
  const float* bi  = (const float*)d_in[3];
  const float* Wh  = (const float*)d_in[4];
  const float* bh  = (const float*)d_in[5];
  const float* Wo  = (const float*)d_in[6];
  const float* bo  = (const float*)d_in[7];
  float* out = (float*)d_out;

  char* w = (char*)d_ws;
  auto alloc = [&](size_t bytes) { char* p = w; w += (bytes + 255) & ~(size_t)255; return p; };
  unsigned short* Ebf    = (unsigned short*)alloc((size_t)V * H * 2);
  unsigned short* Xbf    = (unsigned short*)alloc((size_t)BS * H * 2);
  unsigned short* Wi0bf  = (unsigned short*)alloc((size_t)H * H * 2);
  unsigned short* Wi1bf  = (unsigned short*)alloc((size_t)H * H * 2);
  unsigned short* Wo1bf  = (unsigned short*)alloc((size_t)H * H * 2);
  unsigned short* Wo0Tbf = (unsigned short*)alloc((size_t)H * H * 2);
  float* Mmat  = (float*)alloc((size_t)H * H * 4);
  float* A0f   = (float*)alloc((size_t)BS * H * 4);
  u64*   TH0   = (u64*)alloc((size_t)B * (S + 1) * H * 8);   // tagged {tick|f32}, per-batch layout
  u64*   TH1   = (u64*)alloc((size_t)B * (S + 1) * H * 8);   // adjacent to TH0
  unsigned short* HS1bf = (unsigned short*)alloc((size_t)BS * H * 2);
  unsigned short* OUTbf = (unsigned short*)alloc((size_t)BS * H * 2);
  float* bsum0 = (float*)alloc(H * 4);
  float* c1v   = (float*)alloc(H * 4);
  float* rmax  = (float*)alloc(BS * 4);
  float* rinv  = (float*)alloc(BS * 4);

  const float* Wi0 = Wi;               const float* Wi1 = Wi + (size_t)H * H;
  const float* Wh0 = Wh;               const float* Wh1 = Wh + (size_t)H * H;
  const float* Wo0 = Wo;               const float* Wo1 = Wo + (size_t)H * H;
  const float* bi0 = bi;  const float* bi1 = bi + H;
  const float* bh0 = bh;  const float* bh1 = bh + H;
  const float* bo0 = bo;  const float* bo1 = bo + H;

  const long thn = 2L * B * (S + 1) * H;  // TH0+TH1 are adjacent
  k_zero<<<dim3(2048), dim3(256), 0, stream>>>(TH0, thn);
  k_conv<<<dim3((V * H) / 1024), dim3(256), 0, stream>>>(E, Ebf, V * H);
  k_conv<<<dim3((H * H) / 1024), dim3(256), 0, stream>>>(Wi0, Wi0bf, H * H);
  k_conv<<<dim3((H * H) / 1024), dim3(256), 0, stream>>>(Wi1, Wi1bf, H * H);
  k_conv<<<dim3((H * H) / 1024), dim3(256), 0, stream>>>(Wo1, Wo1bf, H * H);
  k_transconv<<<dim3(32, 32), dim3(256), 0, stream>>>(Wo0, Wo0Tbf);
  k_gather<<<dim3(BS), dim3(256), 0, stream>>>(tokens, E, Xbf);
  k_prep<<<dim3(H), dim3(256), 0, stream>>>(Wi1, bo0, bi0, bi1, bh0, bh1,
                                            c1v, bsum0);

  gemm_bt<2><<<dim3(8, 8), dim3(256), 0, stream>>>(Wi1bf, Wo0Tbf, nullptr, Mmat, H, H, H);
  gemm_bt<0><<<dim3(8, 16), dim3(256), 0, stream>>>(Xbf, Wi0bf, bsum0, A0f, BS, H, H);

  rnn_scan<<<dim3(NBLK), dim3(512), 0, stream>>>(A0f, Wh0, Mmat, Wh1, c1v,
                                                 TH0, TH1, HS1bf);

  gemm_bt<1><<<dim3(8, 16), dim3(256), 0, stream>>>(HS1bf, Wo1bf, bo1, OUTbf, BS, H, H);
  gemm_bt<2><<<dim3(250, 16), dim3(256), 0, stream>>>(OUTbf, Ebf, nullptr, out, BS, V, H);

  k_rowred<<<dim3(BS), dim3(256), 0, stream>>>(out, rmax, rinv);
  k_norm<<<dim3(32, BS), dim3(256), 0, stream>>>(out, rmax, rinv);
}